// Round 2
// baseline (444.633 us; speedup 1.0000x reference)
//
#include <hip/hip_runtime.h>
#include <cstdint>
#include <cstddef>

#define GT_PER_BLOCK 4
#define NTH 256
#define NGT 128
#define BATCH 16
#define NC 80

__device__ __forceinline__ unsigned long long umin64(unsigned long long a, unsigned long long b) {
    return a < b ? a : b;
}

// One block per (level, batch, chunk-of-4-GTs).
// Phase 1: strided scan over HW predictions, per-GT argmin via packed u64 key
//          (d2 bits << 32 | index) -> min gives min-d2 with first-index tie-break,
//          exactly matching jnp.argmin semantics (d2 >= 0 so float bits are
//          monotone as unsigned).
// Phase 2: wave g finishes GT g: 80-class log-softmax via shuffle reductions,
//          L1 on 4 coords, one atomicAdd triple into ws accumulators.
__global__ __launch_bounds__(NTH) void match_loss_kernel(
    const float* __restrict__ cls0, const float* __restrict__ cls1, const float* __restrict__ cls2,
    const float* __restrict__ reg0, const float* __restrict__ reg1, const float* __restrict__ reg2,
    const float* __restrict__ gt_boxes, const int* __restrict__ gt_labels,
    float* __restrict__ acc)
{
    const int chunksPerB = NGT / GT_PER_BLOCK;  // 32
    int idx = blockIdx.x;
    int lvl = idx / (BATCH * chunksPerB);
    int rem = idx % (BATCH * chunksPerB);
    int b = rem / chunksPerB;
    int chunk = rem % chunksPerB;
    int n0 = chunk * GT_PER_BLOCK;

    const float* cls;
    const float* reg;
    int HW;
    if (lvl == 0)      { cls = cls0; reg = reg0; HW = 25600; }
    else if (lvl == 1) { cls = cls1; reg = reg1; HW = 6400; }
    else               { cls = cls2; reg = reg2; HW = 1600; }

    const int tid  = threadIdx.x;
    const int wave = tid >> 6;
    const int lane = tid & 63;

    // GT xy for this block's 4 GTs (uniform loads, L1-cached)
    float gx[GT_PER_BLOCK], gy[GT_PER_BLOCK];
#pragma unroll
    for (int g = 0; g < GT_PER_BLOCK; ++g) {
        const float* gb = gt_boxes + (size_t)(b * NGT + n0 + g) * 4;
        gx[g] = gb[0];
        gy[g] = gb[1];
    }

    const float2* p2 = reinterpret_cast<const float2*>(reg + (size_t)b * HW * 4);
    unsigned long long kmin[GT_PER_BLOCK];
#pragma unroll
    for (int g = 0; g < GT_PER_BLOCK; ++g) kmin[g] = ~0ull;

    for (int i = tid; i < HW; i += NTH) {
        float2 p = p2[(size_t)i * 2];  // xy of pred i (row stride = 16 B)
#pragma unroll
        for (int g = 0; g < GT_PER_BLOCK; ++g) {
            float dx = gx[g] - p.x;
            float dy = gy[g] - p.y;
            float d2 = dx * dx + dy * dy;
            unsigned long long key =
                ((unsigned long long)__float_as_uint(d2) << 32) | (unsigned)i;
            kmin[g] = umin64(kmin[g], key);
        }
    }

    // wave-level reduction of each GT's key
#pragma unroll
    for (int g = 0; g < GT_PER_BLOCK; ++g) {
#pragma unroll
        for (int off = 32; off >= 1; off >>= 1) {
            unsigned long long o = __shfl_down(kmin[g], off, 64);
            kmin[g] = umin64(kmin[g], o);
        }
    }

    __shared__ unsigned long long smem[GT_PER_BLOCK][4];
    if (lane == 0) {
#pragma unroll
        for (int g = 0; g < GT_PER_BLOCK; ++g) smem[g][wave] = kmin[g];
    }
    __syncthreads();

    // Phase 2: wave g handles GT g (4 waves == 4 GTs per block)
    const int g = wave;
    unsigned long long key =
        umin64(umin64(smem[g][0], smem[g][1]), umin64(smem[g][2], smem[g][3]));
    int match = (int)(unsigned)(key & 0xffffffffu);
    float d2min = __uint_as_float((unsigned)(key >> 32));
    bool valid = d2min < 6.25f;  // sqrt(d2) < 2.5

    const int n = n0 + g;
    const int label = gt_labels[b * NGT + n];
    const float* c = cls + ((size_t)b * HW + match) * NC;

    // 80-class log-softmax: lanes 0..63 hold c[lane], lanes 0..15 also c[64+lane]
    float x1 = c[lane];
    float x2 = (lane < NC - 64) ? c[64 + lane] : -INFINITY;
    float mx = fmaxf(x1, x2);
#pragma unroll
    for (int off = 32; off >= 1; off >>= 1) mx = fmaxf(mx, __shfl_xor(mx, off, 64));
    float s = expf(x1 - mx) + ((lane < NC - 64) ? expf(x2 - mx) : 0.0f);
#pragma unroll
    for (int off = 32; off >= 1; off >>= 1) s += __shfl_xor(s, off, 64);

    if (lane == 0 && valid) {
        float xlab = c[label];
        float ce = -(xlab - mx - logf(s));
        const float* gb = gt_boxes + (size_t)(b * NGT + n) * 4;
        const float* gr = reg + ((size_t)b * HW + match) * 4;
        float l1 = fabsf(gr[0] - gb[0]) + fabsf(gr[1] - gb[1]) +
                   fabsf(gr[2] - gb[2]) + fabsf(gr[3] - gb[3]);
        atomicAdd(&acc[0], ce);
        atomicAdd(&acc[1], l1);
        atomicAdd(&acc[2], 1.0f);
    }
}

__global__ void finalize_kernel(const float* __restrict__ acc, float* __restrict__ out) {
    float np = acc[2];
    float denom = fmaxf(np, 1.0f);
    out[0] = acc[0] / denom;
    out[1] = acc[1] / denom;
    out[2] = np;
}

extern "C" void kernel_launch(void* const* d_in, const int* in_sizes, int n_in,
                              void* d_out, int out_size, void* d_ws, size_t ws_size,
                              hipStream_t stream) {
    // Map inputs BY SIZE (setup_inputs() dict order interleaves cls/reg;
    // all 8 element counts are distinct, so this is unambiguous and robust).
    const float* cls0 = nullptr; const float* cls1 = nullptr; const float* cls2 = nullptr;
    const float* reg0 = nullptr; const float* reg1 = nullptr; const float* reg2 = nullptr;
    const float* gt_boxes = nullptr; const int* gt_labels = nullptr;
    for (int i = 0; i < n_in; ++i) {
        switch (in_sizes[i]) {
            case BATCH * 25600 * NC: cls0 = (const float*)d_in[i]; break;   // 32,768,000
            case BATCH * 6400 * NC:  cls1 = (const float*)d_in[i]; break;   //  8,192,000
            case BATCH * 1600 * NC:  cls2 = (const float*)d_in[i]; break;   //  2,048,000
            case BATCH * 25600 * 4:  reg0 = (const float*)d_in[i]; break;   //  1,638,400
            case BATCH * 6400 * 4:   reg1 = (const float*)d_in[i]; break;   //    409,600
            case BATCH * 1600 * 4:   reg2 = (const float*)d_in[i]; break;   //    102,400
            case BATCH * NGT * 4:    gt_boxes = (const float*)d_in[i]; break; //   8,192
            case BATCH * NGT:        gt_labels = (const int*)d_in[i]; break;  //   2,048
            default: break;
        }
    }

    float* acc = (float*)d_ws;
    hipMemsetAsync(d_ws, 0, 3 * sizeof(float), stream);

    const int grid = 3 * BATCH * (NGT / GT_PER_BLOCK);  // 1536 blocks
    match_loss_kernel<<<grid, NTH, 0, stream>>>(
        cls0, cls1, cls2, reg0, reg1, reg2, gt_boxes, gt_labels, acc);

    finalize_kernel<<<1, 1, 0, stream>>>(acc, (float*)d_out);
}